// Round 9
// baseline (1116.123 us; speedup 1.0000x reference)
//
#include <hip/hip_runtime.h>

typedef float f4 __attribute__((ext_vector_type(4)));

constexpr int NN = 100000;
constexpr int NE = 1600000;
constexpr int NBUCK = 512;
constexpr int NPB = 196;           // nodes per bucket: 512*196 = 100352 >= NN
constexpr int ACC_STRIDE = 68;     // padded per-node float stride (bank spread)

__device__ __forceinline__ f4 relu_add(f4 a, f4 b) {
    f4 s = a + b;
    s.x = fmaxf(s.x, 0.f);
    s.y = fmaxf(s.y, 0.f);
    s.z = fmaxf(s.z, 0.f);
    s.w = fmaxf(s.w, 0.f);
    return s;
}

// ---------------- fallback path (used only if ws too small) -------------------

__global__ __launch_bounds__(256) void k_init(const float* __restrict__ x,
                                              const float* __restrict__ eps,
                                              float* __restrict__ out) {
    const float s = 1.0f + eps[0];
    const float4* x4 = (const float4*)x;
    float4* o4 = (float4*)out;
    const int total = NN * 16;
    for (int i = blockIdx.x * blockDim.x + threadIdx.x; i < total;
         i += gridDim.x * blockDim.x) {
        float4 v = x4[i];
        v.x *= s; v.y *= s; v.z *= s; v.w *= s;
        o4[i] = v;
    }
}

__global__ __launch_bounds__(256) void k_edges(const float* __restrict__ x,
                                               const int* __restrict__ ei,
                                               const float* __restrict__ ea,
                                               float* __restrict__ out) {
    const int* dst = ei;
    const int* src = ei + NE;
    const float4* ea4 = (const float4*)ea;
    const float4* x4 = (const float4*)x;
    const int total = NE * 16;
    for (int g = blockIdx.x * blockDim.x + threadIdx.x; g < total;
         g += gridDim.x * blockDim.x) {
        const int e = g >> 4;
        const int c = g & 15;
        const int s = src[e];
        const int d = dst[e];
        float4 a  = ea4[g];
        float4 xv = x4[s * 16 + c];
        float* base = out + d * 64 + c * 4;
        atomicAdd(base + 0, fmaxf(xv.x + a.x, 0.0f));
        atomicAdd(base + 1, fmaxf(xv.y + a.y, 0.0f));
        atomicAdd(base + 2, fmaxf(xv.z + a.z, 0.0f));
        atomicAdd(base + 3, fmaxf(xv.w + a.w, 0.0f));
    }
}

__global__ __launch_bounds__(256) void k_linear2(const float* __restrict__ W,
                                                 const float* __restrict__ bias,
                                                 float* __restrict__ out) {
    __shared__ float Ws[64 * 64];
    __shared__ float bs[64];
    for (int i = threadIdx.x; i < 1024; i += 256)
        ((float4*)Ws)[i] = ((const float4*)W)[i];
    if (threadIdx.x < 16)
        ((float4*)bs)[threadIdx.x] = ((const float4*)bias)[threadIdx.x];
    __syncthreads();

    const int l16 = threadIdx.x & 15;
    const int gid = (blockIdx.x * 256 + threadIdx.x) >> 4;
    const float4* Ws4 = (const float4*)Ws;
    float4* out4 = (float4*)out;

    const float4 h4 = out4[gid * 16 + l16];
    float4 o = ((const float4*)bs)[l16];
#pragma unroll
    for (int d = 0; d < 64; ++d) {
        const int q = d >> 2;
        const int r = d & 3;
        float hd;
        if (r == 0)      hd = __shfl(h4.x, q, 16);
        else if (r == 1) hd = __shfl(h4.y, q, 16);
        else if (r == 2) hd = __shfl(h4.z, q, 16);
        else             hd = __shfl(h4.w, q, 16);
        const float4 w = Ws4[d * 16 + l16];
        o.x = fmaf(hd, w.x, o.x);
        o.y = fmaf(hd, w.y, o.y);
        o.z = fmaf(hd, w.z, o.z);
        o.w = fmaf(hd, w.w, o.w);
    }
    out4[gid * 16 + l16] = o;
}

// ---------------- main path: 512-bucket partition + LDS aggregation -----------

// histogram of dst-range buckets via LDS sub-histogram
__global__ __launch_bounds__(256) void k_hist_b(const int* __restrict__ dst,
                                                int* __restrict__ counts) {
    __shared__ int h[NBUCK];
    for (int i = threadIdx.x; i < NBUCK; i += 256) h[i] = 0;
    __syncthreads();
    const int4* d4 = (const int4*)dst;
    const int total = NE / 4;
    for (int i = blockIdx.x * blockDim.x + threadIdx.x; i < total;
         i += gridDim.x * blockDim.x) {
        const int4 d = d4[i];
        atomicAdd(&h[d.x / NPB], 1);
        atomicAdd(&h[d.y / NPB], 1);
        atomicAdd(&h[d.z / NPB], 1);
        atomicAdd(&h[d.w / NPB], 1);
    }
    __syncthreads();
    for (int i = threadIdx.x; i < NBUCK; i += 256) {
        const int v = h[i];
        if (v) atomicAdd(&counts[i], v);
    }
}

// single-block exclusive scan of the 512 bucket counts
__global__ __launch_bounds__(512) void k_scan_b(const int* __restrict__ counts,
                                                int* __restrict__ offsets,
                                                int* __restrict__ cursor) {
    __shared__ int sd[NBUCK];
    const int t = threadIdx.x;
    const int v = counts[t];
    sd[t] = v;
    __syncthreads();
#pragma unroll
    for (int off = 1; off < NBUCK; off <<= 1) {
        const int u = (t >= off) ? sd[t - off] : 0;
        __syncthreads();
        sd[t] += u;
        __syncthreads();
    }
    const int excl = sd[t] - v;
    offsets[t] = excl;
    cursor[t] = excl;
    if (t == NBUCK - 1) offsets[NBUCK] = NE;
}

// partition descriptors {eid, src | (dstLocal<<17)} into buckets,
// edges processed in original order -> near-monotone eid within each bucket
__global__ __launch_bounds__(256) void k_scatter_b(const int* __restrict__ dst,
                                                   const int* __restrict__ src,
                                                   int* __restrict__ cursor,
                                                   int2* __restrict__ pd) {
    const int4* d4 = (const int4*)dst;
    const int4* s4 = (const int4*)src;
    const int total = NE / 4;
    for (int i = blockIdx.x * blockDim.x + threadIdx.x; i < total;
         i += gridDim.x * blockDim.x) {
        const int4 d = d4[i];
        const int4 s = s4[i];
        const int e = i * 4;
        const int b0 = d.x / NPB, b1 = d.y / NPB, b2 = d.z / NPB, b3 = d.w / NPB;
        const int p0 = atomicAdd(&cursor[b0], 1);
        const int p1 = atomicAdd(&cursor[b1], 1);
        const int p2 = atomicAdd(&cursor[b2], 1);
        const int p3 = atomicAdd(&cursor[b3], 1);
        pd[p0] = make_int2(e + 0, s.x | ((d.x - b0 * NPB) << 17));
        pd[p1] = make_int2(e + 1, s.y | ((d.y - b1 * NPB) << 17));
        pd[p2] = make_int2(e + 2, s.z | ((d.z - b2 * NPB) << 17));
        pd[p3] = make_int2(e + 3, s.w | ((d.w - b3 * NPB) << 17));
    }
}

// One block per bucket: stream descriptors, gather ea (near-monotone) + x (L3),
// accumulate into LDS acc[196][68] via ds float atomics, then fused
// self-term + linear epilogue straight from LDS. src mask: 17 bits (NN<2^17).
__global__ __launch_bounds__(512) void k_agg_b(const float* __restrict__ x,
                                               const float* __restrict__ ea,
                                               const int* __restrict__ offsets,
                                               const int2* __restrict__ pd,
                                               const float* __restrict__ epsp,
                                               const float* __restrict__ W,
                                               const float* __restrict__ bias,
                                               float* __restrict__ out) {
    __shared__ float acc[NPB * ACC_STRIDE];   // 53.3 KB
    __shared__ float Ws[64 * 64];             // 16 KB
    __shared__ float bs[64];

    const int b = blockIdx.x;
    const int base = b * NPB;
    const int cnt = (NN - base < NPB) ? (NN - base) : NPB;  // <=0 for last bucket

    for (int i = threadIdx.x; i < NPB * ACC_STRIDE; i += 512) acc[i] = 0.f;
    for (int i = threadIdx.x; i < 1024; i += 512)
        ((float4*)Ws)[i] = ((const float4*)W)[i];
    if (threadIdx.x < 16)
        ((float4*)bs)[threadIdx.x] = ((const float4*)bias)[threadIdx.x];
    __syncthreads();

    const int l16 = threadIdx.x & 15;
    const int grp = threadIdx.x >> 4;        // 0..31
    const int beg = offsets[b];
    const int end = offsets[b + 1];
    const f4* x4 = (const f4*)x;
    const f4* ea4 = (const f4*)ea;

    int i = beg + grp;
    for (; i + 32 < end; i += 64) {          // 2-deep software pipeline
        const int2 dA = pd[i];
        const int2 dB = pd[i + 32];
        const f4 A0 = ea4[(size_t)dA.x * 16 + l16];
        const f4 X0 = x4[(dA.y & 0x1FFFF) * 16 + l16];
        const f4 A1 = ea4[(size_t)dB.x * 16 + l16];
        const f4 X1 = x4[(dB.y & 0x1FFFF) * 16 + l16];
        const f4 v0 = relu_add(X0, A0);
        const f4 v1 = relu_add(X1, A1);
        float* a0 = &acc[(((unsigned)dA.y) >> 17) * ACC_STRIDE + l16 * 4];
        float* a1 = &acc[(((unsigned)dB.y) >> 17) * ACC_STRIDE + l16 * 4];
        atomicAdd(a0 + 0, v0.x);
        atomicAdd(a0 + 1, v0.y);
        atomicAdd(a0 + 2, v0.z);
        atomicAdd(a0 + 3, v0.w);
        atomicAdd(a1 + 0, v1.x);
        atomicAdd(a1 + 1, v1.y);
        atomicAdd(a1 + 2, v1.z);
        atomicAdd(a1 + 3, v1.w);
    }
    for (; i < end; i += 32) {               // remainder (0 or 1 per group)
        const int2 dA = pd[i];
        const f4 A0 = ea4[(size_t)dA.x * 16 + l16];
        const f4 X0 = x4[(dA.y & 0x1FFFF) * 16 + l16];
        const f4 v0 = relu_add(X0, A0);
        float* a0 = &acc[(((unsigned)dA.y) >> 17) * ACC_STRIDE + l16 * 4];
        atomicAdd(a0 + 0, v0.x);
        atomicAdd(a0 + 1, v0.y);
        atomicAdd(a0 + 2, v0.z);
        atomicAdd(a0 + 3, v0.w);
    }
    __syncthreads();

    // epilogue: h = acc + (1+eps)*x; out = h @ W + b   (per 16-lane group)
    const float epsv = 1.0f + epsp[0];
    const f4* Ws4 = (const f4*)Ws;
    f4* out4 = (f4*)out;
    for (int m = grp; m < cnt; m += 32) {
        const int n = base + m;
        const f4 xs = x4[n * 16 + l16];
        f4 h;
        h.x = fmaf(xs.x, epsv, acc[m * ACC_STRIDE + l16 * 4 + 0]);
        h.y = fmaf(xs.y, epsv, acc[m * ACC_STRIDE + l16 * 4 + 1]);
        h.z = fmaf(xs.z, epsv, acc[m * ACC_STRIDE + l16 * 4 + 2]);
        h.w = fmaf(xs.w, epsv, acc[m * ACC_STRIDE + l16 * 4 + 3]);

        f4 o = ((const f4*)bs)[l16];
#pragma unroll
        for (int d = 0; d < 64; ++d) {
            const int q = d >> 2;
            const int r = d & 3;
            float hd;
            if (r == 0)      hd = __shfl(h.x, q, 16);
            else if (r == 1) hd = __shfl(h.y, q, 16);
            else if (r == 2) hd = __shfl(h.z, q, 16);
            else             hd = __shfl(h.w, q, 16);
            const f4 w = Ws4[d * 16 + l16];
            o.x = fmaf(hd, w.x, o.x);
            o.y = fmaf(hd, w.y, o.y);
            o.z = fmaf(hd, w.z, o.z);
            o.w = fmaf(hd, w.w, o.w);
        }
        out4[n * 16 + l16] = o;
    }
}

extern "C" void kernel_launch(void* const* d_in, const int* in_sizes, int n_in,
                              void* d_out, int out_size, void* d_ws, size_t ws_size,
                              hipStream_t stream) {
    const float* x   = (const float*)d_in[0];
    const int*   ei  = (const int*)d_in[1];
    const float* ea  = (const float*)d_in[2];
    const float* eps = (const float*)d_in[3];
    const float* W   = (const float*)d_in[4];
    const float* b   = (const float*)d_in[5];
    float* out = (float*)d_out;

    const int* dst = ei;        // edge_index[0]
    const int* src = ei + NE;   // edge_index[1]

    // workspace layout: pd first (8B aligned at base)
    int2* pd     = (int2*)d_ws;            // NE
    int* counts  = (int*)(pd + NE);        // NBUCK
    int* offsets = counts + NBUCK;         // NBUCK + 1
    int* cursor  = offsets + NBUCK + 1;    // NBUCK
    const size_t ws_needed = (size_t)(2 * NE + 3 * NBUCK + 1) * sizeof(int);

    if (ws_size < ws_needed) {             // insurance: atomic fallback
        k_init<<<2048, 256, 0, stream>>>(x, eps, out);
        k_edges<<<2048, 256, 0, stream>>>(x, ei, ea, out);
        k_linear2<<<NN * 16 / 256, 256, 0, stream>>>(W, b, out);
        return;
    }

    hipMemsetAsync(counts, 0, (size_t)NBUCK * sizeof(int), stream);
    k_hist_b<<<512, 256, 0, stream>>>(dst, counts);
    k_scan_b<<<1, 512, 0, stream>>>(counts, offsets, cursor);
    k_scatter_b<<<1024, 256, 0, stream>>>(dst, src, cursor, pd);
    k_agg_b<<<NBUCK, 512, 0, stream>>>(x, ea, offsets, pd, eps, W, b, out);
}

// Round 10
// 319.217 us; speedup vs baseline: 3.4964x; 3.4964x over previous
//
#include <hip/hip_runtime.h>

typedef float f4 __attribute__((ext_vector_type(4)));

constexpr int NN = 100000;
constexpr int NE = 1600000;
constexpr int SCAN_BLK = 1024;
constexpr int NB = (NN + SCAN_BLK - 1) / SCAN_BLK;    // 98 scan blocks

__device__ __forceinline__ f4 relu_add(f4 a, f4 b) {
    f4 s = a + b;
    s.x = fmaxf(s.x, 0.f);
    s.y = fmaxf(s.y, 0.f);
    s.z = fmaxf(s.z, 0.f);
    s.w = fmaxf(s.w, 0.f);
    return s;
}

__device__ __forceinline__ f4 bf16x4_to_f4(uint2 u) {
    f4 r;
    r.x = __uint_as_float((u.x & 0xFFFFu) << 16);
    r.y = __uint_as_float(u.x & 0xFFFF0000u);
    r.z = __uint_as_float((u.y & 0xFFFFu) << 16);
    r.w = __uint_as_float(u.y & 0xFFFF0000u);
    return r;
}

__device__ __forceinline__ unsigned short f2bf(float f) {
    unsigned u = __float_as_uint(f);
    u = (u + 0x7FFFu + ((u >> 16) & 1u)) >> 16;   // round-to-nearest-even
    return (unsigned short)u;
}

// ---------------- fallback path (used only if ws too small) -------------------

__global__ __launch_bounds__(256) void k_init(const float* __restrict__ x,
                                              const float* __restrict__ eps,
                                              float* __restrict__ out) {
    const float s = 1.0f + eps[0];
    const float4* x4 = (const float4*)x;
    float4* o4 = (float4*)out;
    const int total = NN * 16;
    for (int i = blockIdx.x * blockDim.x + threadIdx.x; i < total;
         i += gridDim.x * blockDim.x) {
        float4 v = x4[i];
        v.x *= s; v.y *= s; v.z *= s; v.w *= s;
        o4[i] = v;
    }
}

__global__ __launch_bounds__(256) void k_edges(const float* __restrict__ x,
                                               const int* __restrict__ ei,
                                               const float* __restrict__ ea,
                                               float* __restrict__ out) {
    const int* dst = ei;
    const int* src = ei + NE;
    const float4* ea4 = (const float4*)ea;
    const float4* x4 = (const float4*)x;
    const int total = NE * 16;
    for (int g = blockIdx.x * blockDim.x + threadIdx.x; g < total;
         g += gridDim.x * blockDim.x) {
        const int e = g >> 4;
        const int c = g & 15;
        const int s = src[e];
        const int d = dst[e];
        float4 a  = ea4[g];
        float4 xv = x4[s * 16 + c];
        float* base = out + d * 64 + c * 4;
        atomicAdd(base + 0, fmaxf(xv.x + a.x, 0.0f));
        atomicAdd(base + 1, fmaxf(xv.y + a.y, 0.0f));
        atomicAdd(base + 2, fmaxf(xv.z + a.z, 0.0f));
        atomicAdd(base + 3, fmaxf(xv.w + a.w, 0.0f));
    }
}

__global__ __launch_bounds__(256) void k_linear2(const float* __restrict__ W,
                                                 const float* __restrict__ bias,
                                                 float* __restrict__ out) {
    __shared__ float Ws[64 * 64];
    __shared__ float bs[64];
    for (int i = threadIdx.x; i < 1024; i += 256)
        ((float4*)Ws)[i] = ((const float4*)W)[i];
    if (threadIdx.x < 16)
        ((float4*)bs)[threadIdx.x] = ((const float4*)bias)[threadIdx.x];
    __syncthreads();

    const int l16 = threadIdx.x & 15;
    const int gid = (blockIdx.x * 256 + threadIdx.x) >> 4;
    const float4* Ws4 = (const float4*)Ws;
    float4* out4 = (float4*)out;

    const float4 h4 = out4[gid * 16 + l16];
    float4 o = ((const float4*)bs)[l16];
#pragma unroll
    for (int d = 0; d < 64; ++d) {
        const int q = d >> 2;
        const int r = d & 3;
        float hd;
        if (r == 0)      hd = __shfl(h4.x, q, 16);
        else if (r == 1) hd = __shfl(h4.y, q, 16);
        else if (r == 2) hd = __shfl(h4.z, q, 16);
        else             hd = __shfl(h4.w, q, 16);
        const float4 w = Ws4[d * 16 + l16];
        o.x = fmaf(hd, w.x, o.x);
        o.y = fmaf(hd, w.y, o.y);
        o.z = fmaf(hd, w.z, o.z);
        o.w = fmaf(hd, w.w, o.w);
    }
    out4[gid * 16 + l16] = o;
}

// ---------------- main path ----------------------------------------------------

// x (fp32) -> xb (bf16), row-major [NN][64]
__global__ __launch_bounds__(256) void k_cvt_x(const float* __restrict__ x,
                                               unsigned short* __restrict__ xb) {
    const int total = NN * 16;   // float4 count
    const float4* x4 = (const float4*)x;
    for (int i = blockIdx.x * blockDim.x + threadIdx.x; i < total;
         i += gridDim.x * blockDim.x) {
        const float4 v = x4[i];
        ushort4 o;
        o.x = f2bf(v.x); o.y = f2bf(v.y); o.z = f2bf(v.z); o.w = f2bf(v.w);
        ((ushort4*)xb)[i] = o;
    }
}

__global__ __launch_bounds__(256) void k_hist(const int* __restrict__ dst,
                                              int* __restrict__ counts) {
    const int4* d4 = (const int4*)dst;
    const int total = NE / 4;
    for (int i = blockIdx.x * blockDim.x + threadIdx.x; i < total;
         i += gridDim.x * blockDim.x) {
        const int4 d = d4[i];
        atomicAdd(&counts[d.x], 1);
        atomicAdd(&counts[d.y], 1);
        atomicAdd(&counts[d.z], 1);
        atomicAdd(&counts[d.w], 1);
    }
}

__global__ __launch_bounds__(256) void k_scan_block(const int* __restrict__ counts,
                                                    int* __restrict__ offsets,
                                                    int* __restrict__ bsum) {
    __shared__ int sd[256];
    const int t = threadIdx.x;
    const int base = blockIdx.x * SCAN_BLK;
    int c[4];
    int s = 0;
#pragma unroll
    for (int k = 0; k < 4; ++k) {
        const int i = base + t * 4 + k;
        c[k] = (i < NN) ? counts[i] : 0;
        s += c[k];
    }
    sd[t] = s;
    __syncthreads();
#pragma unroll
    for (int off = 1; off < 256; off <<= 1) {
        int v = (t >= off) ? sd[t - off] : 0;
        __syncthreads();
        sd[t] += v;
        __syncthreads();
    }
    int excl = sd[t] - s;
#pragma unroll
    for (int k = 0; k < 4; ++k) {
        const int i = base + t * 4 + k;
        if (i < NN) offsets[i] = excl;
        excl += c[k];
    }
    if (t == 255) bsum[blockIdx.x] = sd[255];
}

__global__ __launch_bounds__(128) void k_scan_sums(const int* __restrict__ bsum,
                                                   int* __restrict__ bsum_ex) {
    __shared__ int sd[128];
    const int t = threadIdx.x;
    const int v = (t < NB) ? bsum[t] : 0;
    sd[t] = v;
    __syncthreads();
#pragma unroll
    for (int off = 1; off < 128; off <<= 1) {
        int u = (t >= off) ? sd[t - off] : 0;
        __syncthreads();
        sd[t] += u;
        __syncthreads();
    }
    bsum_ex[t] = sd[t] - v;
}

__global__ __launch_bounds__(256) void k_scan_add(int* __restrict__ offsets,
                                                  const int* __restrict__ bsum_ex,
                                                  int* __restrict__ cursor) {
    for (int i = blockIdx.x * blockDim.x + threadIdx.x; i < NN;
         i += gridDim.x * blockDim.x) {
        const int v = offsets[i] + bsum_ex[i >> 10];
        offsets[i] = v;
        cursor[i] = v;
    }
    if (blockIdx.x == 0 && threadIdx.x == 0) offsets[NN] = NE;
}

// scatter {edge, src} into dst-sorted order; 4 edges per thread
__global__ __launch_bounds__(256) void k_scatter(const int* __restrict__ dst,
                                                 const int* __restrict__ src,
                                                 int* __restrict__ cursor,
                                                 int2* __restrict__ ps) {
    const int4* d4 = (const int4*)dst;
    const int4* s4 = (const int4*)src;
    const int total = NE / 4;
    for (int i = blockIdx.x * blockDim.x + threadIdx.x; i < total;
         i += gridDim.x * blockDim.x) {
        const int4 d = d4[i];
        const int4 s = s4[i];
        const int e = i * 4;
        int p0 = atomicAdd(&cursor[d.x], 1);
        int p1 = atomicAdd(&cursor[d.y], 1);
        int p2 = atomicAdd(&cursor[d.z], 1);
        int p3 = atomicAdd(&cursor[d.w], 1);
        ps[p0] = make_int2(e + 0, s.x);
        ps[p1] = make_int2(e + 1, s.y);
        ps[p2] = make_int2(e + 2, s.z);
        ps[p3] = make_int2(e + 3, s.w);
    }
}

// Fused per-node aggregation + self-term + linear.
// One node per 16-lane group, 6250 blocks exactly (no early-exit: block count
// divides evenly, so __syncthreads after LDS staging is uniform).
// Edge loop = R7's verified branchless unroll-4 (8 independent row loads in
// flight); x gathered as bf16 (128B rows, L2/L3-resident); self-term from
// exact fp32 x; epilogue = h @ W + b with W in LDS, h broadcast via shfl.
__global__ __launch_bounds__(256, 4) void k_agg_lin(const float* __restrict__ x,
                                                    const unsigned short* __restrict__ xb,
                                                    const float* __restrict__ ea,
                                                    const int* __restrict__ offsets,
                                                    const int2* __restrict__ ps,
                                                    const float* __restrict__ epsp,
                                                    const float* __restrict__ W,
                                                    const float* __restrict__ bias,
                                                    float* __restrict__ out) {
    __shared__ float Ws[64 * 64];
    __shared__ float bs[64];
    for (int i = threadIdx.x; i < 1024; i += 256)
        ((float4*)Ws)[i] = ((const float4*)W)[i];
    if (threadIdx.x < 16)
        ((float4*)bs)[threadIdx.x] = ((const float4*)bias)[threadIdx.x];
    __syncthreads();

    const int l16 = threadIdx.x & 15;
    const int n = (blockIdx.x * 256 + threadIdx.x) >> 4;   // node id, < NN exact
    const float epsv = 1.0f + epsp[0];
    const f4* x4 = (const f4*)x;
    const f4* ea4 = (const f4*)ea;
    const f4* Ws4 = (const f4*)Ws;
    f4* out4 = (f4*)out;

    const int beg = offsets[n];
    const int end = offsets[n + 1];
    f4 acc = {0.f, 0.f, 0.f, 0.f};

    int j = beg;
    for (; j + 4 <= end; j += 4) {
        const int2 d0 = ps[j];
        const int2 d1 = ps[j + 1];
        const int2 d2 = ps[j + 2];
        const int2 d3 = ps[j + 3];
        const f4 A0 = ea4[d0.x * 16 + l16];
        const uint2 xu0 = *(const uint2*)&xb[(size_t)d0.y * 64 + l16 * 4];
        const f4 A1 = ea4[d1.x * 16 + l16];
        const uint2 xu1 = *(const uint2*)&xb[(size_t)d1.y * 64 + l16 * 4];
        const f4 A2 = ea4[d2.x * 16 + l16];
        const uint2 xu2 = *(const uint2*)&xb[(size_t)d2.y * 64 + l16 * 4];
        const f4 A3 = ea4[d3.x * 16 + l16];
        const uint2 xu3 = *(const uint2*)&xb[(size_t)d3.y * 64 + l16 * 4];
        acc += relu_add(bf16x4_to_f4(xu0), A0);
        acc += relu_add(bf16x4_to_f4(xu1), A1);
        acc += relu_add(bf16x4_to_f4(xu2), A2);
        acc += relu_add(bf16x4_to_f4(xu3), A3);
    }
    for (; j < end; ++j) {                   // tail (0..3 edges; also deg<4)
        const int2 d = ps[j];
        const uint2 xu = *(const uint2*)&xb[(size_t)d.y * 64 + l16 * 4];
        acc += relu_add(bf16x4_to_f4(xu), ea4[d.x * 16 + l16]);
    }

    // self term from exact fp32 x
    const f4 xs = x4[n * 16 + l16];
    f4 h;
    h.x = fmaf(xs.x, epsv, acc.x);
    h.y = fmaf(xs.y, epsv, acc.y);
    h.z = fmaf(xs.z, epsv, acc.z);
    h.w = fmaf(xs.w, epsv, acc.w);

    // fused linear: o[l16*4+k] = b + sum_d h[d] * W[d][l16*4+k]
    f4 o = ((const f4*)bs)[l16];
#pragma unroll
    for (int d = 0; d < 64; ++d) {
        const int q = d >> 2;
        const int r = d & 3;
        float hd;
        if (r == 0)      hd = __shfl(h.x, q, 16);
        else if (r == 1) hd = __shfl(h.y, q, 16);
        else if (r == 2) hd = __shfl(h.z, q, 16);
        else             hd = __shfl(h.w, q, 16);
        const f4 w = Ws4[d * 16 + l16];
        o.x = fmaf(hd, w.x, o.x);
        o.y = fmaf(hd, w.y, o.y);
        o.z = fmaf(hd, w.z, o.z);
        o.w = fmaf(hd, w.w, o.w);
    }
    out4[n * 16 + l16] = o;
}

extern "C" void kernel_launch(void* const* d_in, const int* in_sizes, int n_in,
                              void* d_out, int out_size, void* d_ws, size_t ws_size,
                              hipStream_t stream) {
    const float* x   = (const float*)d_in[0];
    const int*   ei  = (const int*)d_in[1];
    const float* ea  = (const float*)d_in[2];
    const float* eps = (const float*)d_in[3];
    const float* W   = (const float*)d_in[4];
    const float* b   = (const float*)d_in[5];
    float* out = (float*)d_out;

    const int* dst = ei;        // edge_index[0]
    const int* src = ei + NE;   // edge_index[1]

    // workspace layout: ps first (8B aligned at base), then xb, then ints
    int2* ps     = (int2*)d_ws;                       // NE
    unsigned short* xb = (unsigned short*)(ps + NE);  // NN*64 bf16
    int* counts  = (int*)(xb + (size_t)NN * 64);      // NN
    int* offsets = counts + NN;                       // NN + 1
    int* cursor  = offsets + NN + 1;                  // NN
    int* bsum    = cursor + NN;                       // 128
    int* bsum_ex = bsum + 128;                        // 128
    const size_t ws_needed = (size_t)NE * 8 + (size_t)NN * 64 * 2 +
                             (size_t)(3 * NN + 1 + 256) * sizeof(int);

    if (ws_size < ws_needed) {            // insurance: atomic fallback
        k_init<<<2048, 256, 0, stream>>>(x, eps, out);
        k_edges<<<2048, 256, 0, stream>>>(x, ei, ea, out);
        k_linear2<<<NN * 16 / 256, 256, 0, stream>>>(W, b, out);
        return;
    }

    hipMemsetAsync(counts, 0, (size_t)NN * sizeof(int), stream);
    k_cvt_x<<<2048, 256, 0, stream>>>(x, xb);
    k_hist<<<1024, 256, 0, stream>>>(dst, counts);
    k_scan_block<<<NB, 256, 0, stream>>>(counts, offsets, bsum);
    k_scan_sums<<<1, 128, 0, stream>>>(bsum, bsum_ex);
    k_scan_add<<<256, 256, 0, stream>>>(offsets, bsum_ex, cursor);
    k_scatter<<<1024, 256, 0, stream>>>(dst, src, cursor, ps);
    k_agg_lin<<<NN * 16 / 256, 256, 0, stream>>>(x, xb, ea, offsets, ps, eps,
                                                 W, b, out);
}